// Round 2
// baseline (1181.743 us; speedup 1.0000x reference)
//
#include <hip/hip_runtime.h>

// Problem: x (32,512,512) fp32 -> pad 128 each side -> (32,768,768)
//          -> nearest-neighbor x4 upsample -> out (32,3072,3072) fp32.
// Interior of output (nonzero) is rows/cols [512, 2560). Both bounds % 4 == 0,
// so every aligned float4 of an output row is either all-zero padding or a
// 4-wide broadcast of a single input element:
//   out[b][i][4*jq .. 4*jq+3] = x[b][(i-512)>>2][jq-128]   for jq in [128,640)
// One coalesced scalar load + one 16B non-temporal store per lane.

// Native clang vector type: __builtin_nontemporal_store requires a pointer to
// scalar-or-vector-of-scalar, not HIP's HIP_vector_type wrapper.
typedef float vfloat4 __attribute__((ext_vector_type(4)));

constexpr int OUTW   = 3072;   // output width/height
constexpr int IN     = 512;
constexpr int Q_LO   = 128;    // first interior quad-col (512/4)
constexpr int Q_HI   = 640;    // one-past-last interior quad-col (2560/4)
constexpr int ROW_LO = 512;    // first interior output row
constexpr int ROW_HI = 2560;   // one-past-last interior output row

__global__ __launch_bounds__(256) void scale_layer_kernel(
    const float* __restrict__ x, float* __restrict__ out) {
    const int i = blockIdx.x;          // output row, 0..3071
    const int b = blockIdx.y;          // batch, 0..31

    vfloat4* orow = reinterpret_cast<vfloat4*>(
        out + ((size_t)b * OUTW + i) * OUTW);

    const bool in_row = (i >= ROW_LO) && (i < ROW_HI);
    // Only dereferenced when in_row; shift of negative is harmless otherwise.
    const float* irow = x + ((size_t)b * IN + ((i - ROW_LO) >> 2)) * IN;

    #pragma unroll
    for (int k = 0; k < 3; ++k) {
        const int jq = (int)threadIdx.x + k * 256;   // quad-column 0..767
        float v = 0.0f;
        if (in_row && jq >= Q_LO && jq < Q_HI) {
            v = irow[jq - Q_LO];                      // coalesced 4B/lane
        }
        vfloat4 vv = {v, v, v, v};
        __builtin_nontemporal_store(vv, &orow[jq]);
    }
}

extern "C" void kernel_launch(void* const* d_in, const int* in_sizes, int n_in,
                              void* d_out, int out_size, void* d_ws, size_t ws_size,
                              hipStream_t stream) {
    const float* x = (const float*)d_in[0];
    float* out = (float*)d_out;
    dim3 grid(OUTW, 32);   // one block per output row per batch sample
    scale_layer_kernel<<<grid, 256, 0, stream>>>(x, out);
}